// Round 3
// baseline (290.441 us; speedup 1.0000x reference)
//
#include <hip/hip_runtime.h>
#include <hip/hip_bf16.h>
#include <stdint.h>

// ---- problem constants ----
#define B64   64
#define DIMS  120
#define NLOC  (DIMS*DIMS)      // 14400 V1 locations
#define V4D   29
#define NLOC4 (V4D*V4D)        // 841 V4 locations

typedef __attribute__((ext_vector_type(8))) short bf16x8;  // 8 bf16 in 4 VGPRs
typedef __attribute__((ext_vector_type(4))) float f32x4;

__device__ __forceinline__ unsigned short f2bf(float f) {
    unsigned u = __float_as_uint(f);
    u += 0x7fffu + ((u >> 16) & 1u);   // round-to-nearest-even
    return (unsigned short)(u >> 16);
}

// ------------------------------------------------------------------
// k0: pack x into two bf16 replica tensors with b innermost for coalesced
// MFMA A-fragment loads (16 lanes x 16B = 256B contiguous per quarter):
//   xrep [r][col][g][b][q]  = x[b][8g+r+q][col]   (rows chunked)
//   xrepT[rc][row][gc][b][q] = x[b][row][8gc+rc+q] (cols chunked)
// ------------------------------------------------------------------
__global__ __launch_bounds__(256) void k0_pack(const float* __restrict__ x,
                                               unsigned short* __restrict__ xrep,
                                               unsigned short* __restrict__ xrepT) {
    __shared__ unsigned short tile[16 * 16 * 64];   // [d1][d2][b]
    int blk = blockIdx.x;
    int isT = (blk >= 128) ? 1 : 0;
    int b2 = blk - 128 * isT;
    int g = b2 >> 3;             // chunk index 0..15
    int fb = (b2 & 7) << 4;      // fixed-dim block base
    int tid = threadIdx.x;
    int bb = tid >> 2, c4 = (tid & 3) << 2;
#pragma unroll 4
    for (int rr = 0; rr < 16; ++rr) {
        int row, col;
        if (!isT) { row = 8 * g + rr; col = fb + c4; }
        else      { row = fb + rr;    col = 8 * g + c4; }
        f32x4 v;
        if (row < 128 && col < 128)
            v = *(const f32x4*)(x + ((size_t)bb * 128 + row) * 128 + col);
        else
            v = (f32x4){0.f, 0.f, 0.f, 0.f};
#pragma unroll
        for (int cc = 0; cc < 4; ++cc) {
            int d1 = isT ? rr : (c4 + cc);
            int d2 = isT ? (c4 + cc) : rr;
            tile[(d1 * 16 + d2) * 64 + bb] = f2bf(v[cc]);
        }
    }
    __syncthreads();
    unsigned short* outp = isT ? xrepT : xrep;
    int b = tid & 63;
#pragma unroll
    for (int it = 0; it < 32; ++it) {
        int u = (it * 256 + tid) >> 6;   // 0..127
        int d1 = u & 15, rq = u >> 4;    // rq = r (or rc), 0..7
        bf16x8 pk;
#pragma unroll
        for (int q = 0; q < 8; ++q)
            pk[q] = (short)tile[(d1 * 16 + rq + q) * 64 + b];
        size_t off = ((((size_t)rq * 128 + (fb + d1)) * 16 + g) * 64 + b) * 8;
        *(bf16x8*)(outp + off) = pk;
    }
}

// ------------------------------------------------------------------
// k1: V1 locally-connected + relu + phase-mean. One wave per location,
// 4 consecutive locations per block. K = 96 (3 MFMA K-steps),
// chunk ch = ks*4 + t:
//   ch 0..8 : patch col kw=ch, rows i..i+7   -> xrep  (kh = jj)
//   ch 9    : row i+8, cols j..j+7           -> xrepT (kw = jj)
//   ch 10   : row i+8, col j+8 (jj==0 only)  -> xrepT at gc+1
//   ch 11   : pad (zeros)
// B staged K-major in LDS: stage[w][c][13*8] bf16, slot = ch*8+jj
//   (= e<72 ? (e%9)*8+e/9 : e). Row stride 104 elem (52 words): b128 reads
//   hit every bank exactly 8x (the phase minimum) -> conflict-free.
// B-frag = ONE ds_read_b128, branch-free across all K-steps.
// ------------------------------------------------------------------
__global__ __launch_bounds__(256) void k1_v1(const unsigned short* __restrict__ xrep,
                                             const unsigned short* __restrict__ xrepT,
                                             const float* __restrict__ sw,
                                             unsigned short* __restrict__ cplx) {
    __shared__ __align__(16) char smraw[4 * 32 * 104 * 2];   // 26624 B
    unsigned short* stage = (unsigned short*)smraw;           // [w][c][104] bf16
    float* pool2 = (float*)smraw;                             // [w][64][9] fp32 (9216 B, overlaid)

    int tid = threadIdx.x;
    int blk = blockIdx.x;
    int blk2 = (blk & 7) * 450 + (blk >> 3);   // XCD band swizzle (3600 = 8*450)
    int loc0 = blk2 * 4;

    // ---- zero pad slots (chunk10 jj1-7 + chunk11) ----
    if (tid < 128) {
        unsigned short* rowp = stage + tid * 104;   // tid = w*32+c
#pragma unroll
        for (int z = 81; z < 96; ++z) rowp[z] = 0;
    }
    // ---- stage simple_weight for 4 locations: 2592 dwordx4, coalesced ----
#pragma unroll
    for (int it = 0; it < 11; ++it) {
        int idx = it * 256 + tid;
        if (idx < 2592) {
            int c = idx / 81, r4 = idx - c * 81;
            f32x4 v = *(const f32x4*)(sw + ((size_t)c * NLOC + loc0) * 81 + r4 * 4);
            int posf = r4 * 4;
#pragma unroll
            for (int qq = 0; qq < 4; ++qq) {
                int pp = posf + qq;          // 0..323 = w2*81 + e
                int w2 = 0, e = pp;
                if (e >= 162) { w2 = 2; e -= 162; }
                if (e >= 81)  { w2 += 1; e -= 81; }
                int slot;
                if (e < 72) { int jj = e / 9; slot = (e - 9 * jj) * 8 + jj; }
                else        { slot = e; }
                stage[(w2 * 32 + c) * 104 + slot] = f2bf(v[qq]);
            }
        }
    }
    __syncthreads();

    int w = tid >> 6, l = tid & 63;
    int loc = loc0 + w;
    int i = loc / DIMS, j = loc - i * DIMS;
    int ln = l & 15, t = l >> 4;
    int r = i & 7, g = i >> 3, rc = j & 7, gc = j >> 3;
    const unsigned short* stw = stage + w * 32 * 104;

    f32x4 acc[4][2];
#pragma unroll
    for (int mt = 0; mt < 4; ++mt)
#pragma unroll
        for (int nt = 0; nt < 2; ++nt)
            acc[mt][nt] = (f32x4){0.f, 0.f, 0.f, 0.f};

#pragma unroll
    for (int ks = 0; ks < 3; ++ks) {
        int ch = ks * 4 + t;
        // ---- A fragments ----
        const unsigned short* abase;
        if (ks < 2) {
            int col = j + ch;    // ch <= 7 here
            abase = xrep + (((size_t)r * 128 + col) * 16 + g) * 512;
        } else {
            const unsigned short* a0 = xrep + (((size_t)r * 128 + (j + 8)) * 16 + g) * 512;
            int gc2 = gc + ((t >= 2) ? 1 : 0);
            const unsigned short* a1 = xrepT + (((size_t)rc * 128 + (i + 8)) * 16 + gc2) * 512;
            abase = (t == 0) ? a0 : a1;
        }
        bf16x8 a[4];
#pragma unroll
        for (int mt = 0; mt < 4; ++mt)
            a[mt] = *(const bf16x8*)(abase + (size_t)(ln + 16 * mt) * 8);
        // ---- B fragments: one ds_read_b128 each, branch-free ----
        bf16x8 bfr[2];
#pragma unroll
        for (int nt = 0; nt < 2; ++nt)
            bfr[nt] = *(const bf16x8*)(stw + (ln + 16 * nt) * 104 + ch * 8);
        // ---- MFMAs ----
#pragma unroll
        for (int mt = 0; mt < 4; ++mt)
#pragma unroll
            for (int nt = 0; nt < 2; ++nt)
                acc[mt][nt] = __builtin_amdgcn_mfma_f32_16x16x32_bf16(
                    a[mt], bfr[nt], acc[mt][nt], 0, 0, 0);
    }

    // ---- epilogue: relu, phase-mean via shfl_xor, LDS transpose, store ----
    __syncthreads();                     // stage dead; pool2 overlays it
    float* pl = pool2 + w * 64 * 9;
#pragma unroll
    for (int mt = 0; mt < 4; ++mt)
#pragma unroll
        for (int nt = 0; nt < 2; ++nt)
#pragma unroll
            for (int reg = 0; reg < 4; ++reg) {
                float v = fmaxf(acc[mt][nt][reg], 0.0f);
                v += __shfl_xor(v, 1, 64);
                v += __shfl_xor(v, 2, 64);
                if ((ln & 3) == 0) {
                    int b = 16 * mt + 4 * t + reg;
                    int s = 4 * nt + (ln >> 2);
                    pl[b * 9 + s] = v * 0.25f;
                }
            }
    __syncthreads();
    bf16x8 po;
#pragma unroll
    for (int s = 0; s < 8; ++s)
        po[s] = (short)f2bf(pl[l * 9 + s]);
    *(bf16x8*)(cplx + (size_t)loc * 512 + l * 8) = po;
}

// ------------------------------------------------------------------
// k2: V4 pooling. One block per location; vw slice staged bf16 in LDS as
// stg2[pos][o][s] (16 KB) so each B-frag is ONE ds_read_b128 (bank-minimal).
// 4 waves split K (4 MFMA K-steps each), LDS reduce across waves.
// ------------------------------------------------------------------
__global__ __launch_bounds__(256) void k2_v4(const unsigned short* __restrict__ cplx,
                                             const float* __restrict__ vw,
                                             float* __restrict__ v4s) {
    __shared__ __align__(16) char smraw[16384];
    unsigned short* stg2 = (unsigned short*)smraw;   // [64 pos][16 o][8 s] bf16
    float* pool = (float*)smraw;                     // [4][64][16] fp32 (overlaid)

    int tid = threadIdx.x;
    int blk = blockIdx.x;
    int loc = (blk < 840) ? ((blk & 7) * 105 + (blk >> 3)) : 840;  // XCD band swizzle
    int oi = loc / V4D, oj = loc - oi * V4D;

    // ---- stage vw[.,.,loc,.]: 2048 dwordx4 coalesced, bf16-convert ----
#pragma unroll
    for (int it = 0; it < 8; ++it) {
        int idx = it * 256 + tid;
        int row = idx >> 4, p4 = (idx & 15) * 4;     // row = o*8+s
        f32x4 v = *(const f32x4*)(vw + ((size_t)row * NLOC4 + loc) * 64 + p4);
        int o = row >> 3, s = row & 7;
#pragma unroll
        for (int qq = 0; qq < 4; ++qq)
            stg2[((p4 + qq) * 16 + o) * 8 + s] = f2bf(v[qq]);
    }
    __syncthreads();

    int w = tid >> 6, l = tid & 63;
    int ln = l & 15, t = l >> 4;
    f32x4 acc[4];
#pragma unroll
    for (int mt = 0; mt < 4; ++mt) acc[mt] = (f32x4){0.f, 0.f, 0.f, 0.f};

#pragma unroll
    for (int kk = 0; kk < 4; ++kk) {
        int pos = 4 * (w * 4 + kk) + t;      // 0..63
        int kh = pos >> 3, kw = pos & 7;
        int iloc = (oi * 4 + kh) * DIMS + oj * 4 + kw;
        const unsigned short* ab = cplx + (size_t)iloc * 512 + ln * 8;
        bf16x8 a[4];
#pragma unroll
        for (int mt = 0; mt < 4; ++mt)
            a[mt] = *(const bf16x8*)(ab + mt * 128);
        bf16x8 bb = *(const bf16x8*)(stg2 + (pos * 16 + ln) * 8);
#pragma unroll
        for (int mt = 0; mt < 4; ++mt)
            acc[mt] = __builtin_amdgcn_mfma_f32_16x16x32_bf16(a[mt], bb, acc[mt], 0, 0, 0);
    }
    __syncthreads();                       // stg2 dead; pool overlays
#pragma unroll
    for (int mt = 0; mt < 4; ++mt)
#pragma unroll
        for (int reg = 0; reg < 4; ++reg)
            pool[((w * 64) + 16 * mt + 4 * t + reg) * 16 + ln] = acc[mt][reg];
    __syncthreads();
    int o = tid & 15, brow = tid >> 4;
#pragma unroll
    for (int itb = 0; itb < 4; ++itb) {
        int b = brow + 16 * itb;
        float s = pool[(0 * 64 + b) * 16 + o] + pool[(1 * 64 + b) * 16 + o] +
                  pool[(2 * 64 + b) * 16 + o] + pool[(3 * 64 + b) * 16 + o];
        v4s[(size_t)loc * 1024 + b * 16 + o] = s;
    }
}

// ------------------------------------------------------------------
// k3: decision readout. One block per batch element.
// ------------------------------------------------------------------
__global__ __launch_bounds__(256) void k3_dec(const float* __restrict__ v4s,
                                              const float* __restrict__ dw,
                                              const float* __restrict__ db,
                                              float* __restrict__ out) {
    int b = blockIdx.x, tid = threadIdx.x;
    float a0 = 0.f, a1 = 0.f;
    for (int loc = tid; loc < NLOC4; loc += 256) {
        const float* vp = v4s + (size_t)loc * 1024 + b * 16;
#pragma unroll
        for (int o4 = 0; o4 < 4; ++o4) {
            f32x4 v = *(const f32x4*)(vp + o4 * 4);
#pragma unroll
            for (int q = 0; q < 4; ++q) {
                int o = o4 * 4 + q;
                a0 += v[q] * dw[o * NLOC4 + loc];
                a1 += v[q] * dw[16 * NLOC4 + o * NLOC4 + loc];
            }
        }
    }
    __shared__ float r0[256], r1[256];
    r0[tid] = a0; r1[tid] = a1;
    __syncthreads();
    for (int s = 128; s > 0; s >>= 1) {
        if (tid < s) { r0[tid] += r0[tid + s]; r1[tid] += r1[tid + s]; }
        __syncthreads();
    }
    if (tid == 0) {
        out[2 * b + 0] = r0[0] + db[0];
        out[2 * b + 1] = r1[0] + db[1];
    }
}

// ------------------------------------------------------------------
extern "C" void kernel_launch(void* const* d_in, const int* in_sizes, int n_in,
                              void* d_out, int out_size, void* d_ws, size_t ws_size,
                              hipStream_t stream) {
    const float* x  = (const float*)d_in[0];   // [64][1][128][128]
    const float* sw = (const float*)d_in[1];   // [32][120][120][81]
    const float* vw = (const float*)d_in[2];   // [16][8][29][29][64]
    const float* dw = (const float*)d_in[3];   // [2][13456]
    const float* db = (const float*)d_in[4];   // [2]
    float* out = (float*)d_out;                // [64][2]

    char* ws = (char*)d_ws;
    unsigned short* xrep  = (unsigned short*)ws;                         // 16,777,216 B
    unsigned short* xrepT = (unsigned short*)(ws + 16777216);            // 16,777,216 B
    unsigned short* cplx  = (unsigned short*)(ws + 33554432);            // 14,745,600 B
    float*          v4s   = (float*)(ws + 48300032);                     //  3,444,736 B

    k0_pack<<<256, 256, 0, stream>>>(x, xrep, xrepT);
    k1_v1<<<NLOC / 4, 256, 0, stream>>>(xrep, xrepT, sw, cplx);
    k2_v4<<<NLOC4, 256, 0, stream>>>(cplx, vw, v4s);
    k3_dec<<<B64, 256, 0, stream>>>(v4s, dw, db, out);
}